// Round 1
// 1079.536 us; speedup vs baseline: 1.0514x; 1.0514x over previous
//
#include <hip/hip_runtime.h>
#include <hip/hip_bf16.h>
#include <stdint.h>
#include <stdio.h>

// Problem dims (fixed by the reference)
#define T_SEQ  2048
#define BATCH  2
#define NROWS  4096   // B*T
#define EMBED  512
#define HIDDEN 1024
#define VOCAB  32000
#define NCHUNK 32
#define CHLEN  64     // T_SEQ / NCHUNK

typedef __bf16 bf16x8 __attribute__((ext_vector_type(8)));
typedef float  f32x4  __attribute__((ext_vector_type(4)));

__device__ __forceinline__ float b2f(unsigned short h) {
  union { unsigned int u; float f; } v; v.u = ((unsigned int)h) << 16; return v.f;
}
__device__ __forceinline__ unsigned short f2b(float f) {
  union { float f; unsigned int u; } v; v.f = f;
  unsigned int u = v.u;
  u += 0x7fffu + ((u >> 16) & 1u);   // round-to-nearest-even
  return (unsigned short)(u >> 16);
}

// ---------------- gather: emb[row,:] = bf16(E[tokens[row],:]) ----------------
__global__ void gather_kernel(const int* __restrict__ tokens,
                              const float* __restrict__ E,
                              unsigned short* __restrict__ emb) {
  const int row = blockIdx.x;
  const int tok = tokens[row];
  const float2 v = ((const float2*)(E + (size_t)tok * EMBED))[threadIdx.x];
  const uint32_t packed = (uint32_t)f2b(v.x) | ((uint32_t)f2b(v.y) << 16);
  ((uint32_t*)(emb + (size_t)row * EMBED))[threadIdx.x] = packed;  // 256 thr * 2 bf16
}

// ------------- prefix mean, 3-pass chunked scan -------------
// hist[t] = mean(emb[0:t]) = csum[t-1]/t for t>=1; hist[0] = emb[0]
__global__ void scan_sum_kernel(const unsigned short* __restrict__ emb,
                                float* __restrict__ csum) {
  const int bc = blockIdx.x;                 // b*NCHUNK + c
  const int d  = threadIdx.x;
  const unsigned short* e = emb + ((size_t)bc * CHLEN) * EMBED + d;
  float s = 0.f;
  #pragma unroll 8
  for (int i = 0; i < CHLEN; ++i) s += b2f(e[(size_t)i * EMBED]);
  csum[(size_t)bc * EMBED + d] = s;
}

__global__ void scan_excl_kernel(float* __restrict__ csum) {
  const int b = blockIdx.x;
  const int d = threadIdx.x;
  float run = 0.f;
  for (int c = 0; c < NCHUNK; ++c) {
    const size_t idx = ((size_t)b * NCHUNK + c) * EMBED + d;
    const float v = csum[idx];
    csum[idx] = run;
    run += v;
  }
}

__global__ void scan_emit_kernel(const unsigned short* __restrict__ emb,
                                 const float* __restrict__ csum,
                                 unsigned short* __restrict__ hist) {
  const int bc = blockIdx.x;                 // b*NCHUNK + c
  const int c  = bc & (NCHUNK - 1);
  const int d  = threadIdx.x;
  const unsigned short* e = emb  + ((size_t)bc * CHLEN) * EMBED + d;
  unsigned short*       h = hist + ((size_t)bc * CHLEN) * EMBED + d;
  float sum = csum[(size_t)bc * EMBED + d];  // exclusive prefix Σ emb[0 .. c*CHLEN-1]
  #pragma unroll 8
  for (int i = 0; i < CHLEN; ++i) {
    const int t = c * CHLEN + i;             // global timestep within batch
    h[(size_t)i * EMBED] = (t == 0) ? e[0] : f2b(sum / (float)t);
    sum += b2f(e[(size_t)i * EMBED]);
  }
}

// ------------- transpose + f32->bf16 cast: out[C,R] = bf16(in[R,C]^T) -------------
__global__ void transpose_cast_kernel(const float* __restrict__ in,
                                      unsigned short* __restrict__ out,
                                      int R, int C) {
  __shared__ float tile[32][33];             // +1 pad breaks bank conflicts
  const int tx = threadIdx.x & 31;
  const int ty = threadIdx.x >> 5;           // 0..7
  const int r0 = blockIdx.y * 32, c0 = blockIdx.x * 32;
  #pragma unroll
  for (int i = 0; i < 32; i += 8)
    tile[ty + i][tx] = in[(size_t)(r0 + ty + i) * C + (c0 + tx)];
  __syncthreads();
  #pragma unroll
  for (int i = 0; i < 32; i += 8)
    out[(size_t)(c0 + ty + i) * R + (r0 + tx)] = f2b(tile[tx][ty + i]);
}

// ---------------- MFMA GEMM: out = f(A @ BT^T + bias) ----------------
// A [M,K] bf16 row-major, BT [N,K] bf16 row-major (B pre-transposed).
// MODE 0: relu -> bf16 ; MODE 1: relu -> f32 ; MODE 2: (x+bias)*0.1 -> f32 (NT stores)
// Grid is 1D over (M/BM)*(N/BN) tiles; in-kernel bijective XCD chunk swizzle
// (m204) + m-fastest tile order: 32 consecutive blocks share one B-panel and
// land on the same XCD's L2 -> B^T fetched ~once from HBM instead of ~16x.
// blockIdx.z==1 selects the second (A2,BT2,bias2,colOff2) problem (encode fusion).
#define BM 128
#define BN 128
#define BK 32

__device__ __forceinline__ void async16(unsigned short* lds, const unsigned short* g) {
  __builtin_amdgcn_global_load_lds(
      (const __attribute__((address_space(1))) void*)g,
      (__attribute__((address_space(3))) void*)lds, 16, 0, 0);
}

template<int MODE>
__global__ __launch_bounds__(256) void gemm_bt_kernel(
    const unsigned short* __restrict__ A,
    const unsigned short* __restrict__ BT,
    const float* __restrict__ bias,
    void* __restrict__ out, int M, int N, int K, int ldOut, int colOff,
    const unsigned short* __restrict__ A2,
    const unsigned short* __restrict__ BT2,
    const float* __restrict__ bias2, int colOff2) {
  __shared__ unsigned short As[BM * BK];   // [128][32] row-major
  __shared__ unsigned short Bs[BN * BK];   // [128][32] row-major (n-major)

  const unsigned short* Ap = A;
  const unsigned short* Bp = BT;
  const float*          bp = bias;
  int                   co = colOff;
  if (blockIdx.z) { Ap = A2; Bp = BT2; bp = bias2; co = colOff2; }

  // --- bijective XCD chunk swizzle (m204) + m-fastest decomposition ---
  int wg = blockIdx.x;
  {
    const int nwg = gridDim.x;
    const int xcd = wg & 7, loc = wg >> 3;
    const int q = nwg >> 3, r = nwg & 7;
    wg = (xcd < r ? xcd * (q + 1) : r * (q + 1) + (xcd - r) * q) + loc;
  }
  const int nmb = M / BM;
  const int mb  = wg % nmb;                // fastest -> consecutive blocks share B-panel
  const int nb  = wg / nmb;
  const int m0  = mb * BM;
  const int n0  = nb * BN;

  const int tid  = threadIdx.x;
  const int wave = tid >> 6;
  const int lane = tid & 63;
  const int wm = (wave & 1) * 64;          // wave quadrant (2x2)
  const int wn = (wave >> 1) * 64;

  // staging: each wave stages its own 32-row chunk of each tile (2 instrs x 1KB)
  const int srow = (wave << 5) + (lane >> 2);   // +16 rows on 2nd instr
  const int scol = (lane & 3) << 3;             // 4 lanes x 8 bf16 = 32 k
  const unsigned short* aSrc = Ap + (size_t)(m0 + srow) * K + scol;
  const unsigned short* bSrc = Bp + (size_t)(n0 + srow) * K + scol;
  unsigned short* aDst = As + (wave << 5) * BK;  // wave-uniform LDS base
  unsigned short* bDst = Bs + (wave << 5) * BK;

  f32x4 acc[4][4];
  #pragma unroll
  for (int i = 0; i < 4; ++i)
    #pragma unroll
    for (int j = 0; j < 4; ++j)
      acc[i][j] = (f32x4){0.f, 0.f, 0.f, 0.f};

  const int q = lane >> 4;   // k-group (frags) / row-group (C/D)
  const int r = lane & 15;   // m (A) / n (B,C/D) index within 16-tile

  for (int k0 = 0; k0 < K; k0 += BK) {
    __syncthreads();                              // LDS free (prev reads done)
    async16(aDst,           aSrc);
    async16(aDst + 16 * BK, aSrc + 16 * (size_t)K);
    async16(bDst,           bSrc);
    async16(bDst + 16 * BK, bSrc + 16 * (size_t)K);
    aSrc += BK; bSrc += BK;
    __syncthreads();                              // drains vmcnt before use

    bf16x8 af[4], bfr[4];
    #pragma unroll
    for (int mi = 0; mi < 4; ++mi)
      af[mi] = *(const bf16x8*)&As[(wm + mi * 16 + r) * BK + (q << 3)];
    #pragma unroll
    for (int ni = 0; ni < 4; ++ni)
      bfr[ni] = *(const bf16x8*)&Bs[(wn + ni * 16 + r) * BK + (q << 3)];
    #pragma unroll
    for (int mi = 0; mi < 4; ++mi)
      #pragma unroll
      for (int ni = 0; ni < 4; ++ni)
        acc[mi][ni] = __builtin_amdgcn_mfma_f32_16x16x32_bf16(
            af[mi], bfr[ni], acc[mi][ni], 0, 0, 0);
  }

  // epilogue: C/D layout col=lane&15, row=(lane>>4)*4+e  [verified m89/m91]
  #pragma unroll
  for (int ni = 0; ni < 4; ++ni) {
    const int col = n0 + wn + ni * 16 + r;
    const float bv = bp[col];
    #pragma unroll
    for (int mi = 0; mi < 4; ++mi) {
      #pragma unroll
      for (int e = 0; e < 4; ++e) {
        const int row = m0 + wm + mi * 16 + (q << 2) + e;
        float v = acc[mi][ni][e] + bv;
        if (MODE == 0 || MODE == 1) v = fmaxf(v, 0.f);
        if (MODE == 2) v *= 0.1f;
        const size_t idx = (size_t)row * ldOut + co + col;
        if (MODE == 0)      ((unsigned short*)out)[idx] = f2b(v);
        else if (MODE == 1) ((float*)out)[idx] = v;
        else                __builtin_nontemporal_store(v, &((float*)out)[idx]);
      }
    }
  }
}

// ---------------- LayerNorm over last dim (1024), f32 in -> bf16 out ----------------
__global__ void ln_kernel(const float* __restrict__ merged,
                          const float* __restrict__ lnw,
                          const float* __restrict__ lnb,
                          unsigned short* __restrict__ normed) {
  const int row = blockIdx.x;
  const float4 v = ((const float4*)(merged + (size_t)row * HIDDEN))[threadIdx.x];
  float s  = v.x + v.y + v.z + v.w;
  float ss = v.x * v.x + v.y * v.y + v.z * v.z + v.w * v.w;
  #pragma unroll
  for (int off = 32; off > 0; off >>= 1) {
    s  += __shfl_down(s, off, 64);
    ss += __shfl_down(ss, off, 64);
  }
  __shared__ float red[8];
  const int wvi = threadIdx.x >> 6;
  if ((threadIdx.x & 63) == 0) { red[wvi] = s; red[4 + wvi] = ss; }
  __syncthreads();
  s  = red[0] + red[1] + red[2] + red[3];
  ss = red[4] + red[5] + red[6] + red[7];
  const float mu  = s * (1.0f / HIDDEN);
  const float var = ss * (1.0f / HIDDEN) - mu * mu;
  const float rs  = rsqrtf(var + 1e-5f);
  const float4 w4 = ((const float4*)lnw)[threadIdx.x];
  const float4 b4 = ((const float4*)lnb)[threadIdx.x];
  ushort4 o;
  o.x = f2b((v.x - mu) * rs * w4.x + b4.x);
  o.y = f2b((v.y - mu) * rs * w4.y + b4.y);
  o.z = f2b((v.z - mu) * rs * w4.z + b4.z);
  o.w = f2b((v.w - mu) * rs * w4.w + b4.w);
  ((ushort4*)(normed + (size_t)row * HIDDEN))[threadIdx.x] = o;
}

extern "C" void kernel_launch(void* const* d_in, const int* in_sizes, int n_in,
                              void* d_out, int out_size, void* d_ws, size_t ws_size,
                              hipStream_t stream) {
  const int*   tokens = (const int*)d_in[0];
  const float* E      = (const float*)d_in[1];
  const float* Wc     = (const float*)d_in[2];
  const float* bc     = (const float*)d_in[3];
  const float* Wh     = (const float*)d_in[4];
  const float* bh     = (const float*)d_in[5];
  const float* Wm     = (const float*)d_in[6];
  const float* bm     = (const float*)d_in[7];
  const float* Wo     = (const float*)d_in[8];
  const float* bo     = (const float*)d_in[9];
  const float* lnw    = (const float*)d_in[10];
  const float* lnb    = (const float*)d_in[11];

  char* p = (char*)d_ws;
  unsigned short* WcT  = (unsigned short*)p; p += (size_t)HIDDEN * EMBED * 2;
  unsigned short* WhT  = (unsigned short*)p; p += (size_t)HIDDEN * EMBED * 2;
  unsigned short* WmT  = (unsigned short*)p; p += (size_t)HIDDEN * (2 * HIDDEN) * 2;
  unsigned short* WoT  = (unsigned short*)p; p += (size_t)VOCAB * HIDDEN * 2;
  unsigned short* emb  = (unsigned short*)p; p += (size_t)NROWS * EMBED * 2;
  unsigned short* hist = (unsigned short*)p; p += (size_t)NROWS * EMBED * 2;
  unsigned short* cat  = (unsigned short*)p; p += (size_t)NROWS * (2 * HIDDEN) * 2;
  float*          mrg  = (float*)p;          p += (size_t)NROWS * HIDDEN * 4;
  unsigned short* nrm  = (unsigned short*)p; p += (size_t)NROWS * HIDDEN * 2;
  float*          csum = (float*)p;          p += (size_t)BATCH * NCHUNK * EMBED * 4;
  if ((size_t)(p - (char*)d_ws) > ws_size)
    fprintf(stderr, "WS TOO SMALL: need %zu have %zu\n", (size_t)(p - (char*)d_ws), ws_size);

  // weight pre-transposes + f32->bf16 cast (GEMM consumes B^T [N,K] bf16)
  transpose_cast_kernel<<<dim3(HIDDEN / 32, EMBED / 32), 256, 0, stream>>>(Wc, WcT, EMBED, HIDDEN);
  transpose_cast_kernel<<<dim3(HIDDEN / 32, EMBED / 32), 256, 0, stream>>>(Wh, WhT, EMBED, HIDDEN);
  transpose_cast_kernel<<<dim3(HIDDEN / 32, (2 * HIDDEN) / 32), 256, 0, stream>>>(Wm, WmT, 2 * HIDDEN, HIDDEN);
  transpose_cast_kernel<<<dim3(VOCAB / 32, HIDDEN / 32), 256, 0, stream>>>(Wo, WoT, HIDDEN, VOCAB);

  gather_kernel<<<NROWS, 256, 0, stream>>>(tokens, E, emb);
  scan_sum_kernel <<<BATCH * NCHUNK, EMBED, 0, stream>>>(emb, csum);
  scan_excl_kernel<<<BATCH, EMBED, 0, stream>>>(csum);
  scan_emit_kernel<<<BATCH * NCHUNK, EMBED, 0, stream>>>(emb, csum, hist);

  const int nwgEnc = (NROWS / BM) * (HIDDEN / BN);   // 256 tiles per slice
  const int nwgOut = (NROWS / BM) * (VOCAB / BN);    // 8000 tiles

  // cur_enc / hist_enc fused into one launch (z=2) -> concatenated [4096, 2048] bf16
  gemm_bt_kernel<0><<<dim3(nwgEnc, 1, 2), 256, 0, stream>>>(
      emb, WcT, bc, cat, NROWS, HIDDEN, EMBED, 2 * HIDDEN, 0,
      hist, WhT, bh, HIDDEN);
  // merged = relu(cat @ Wm + bm), kept f32 for LN accuracy
  gemm_bt_kernel<1><<<dim3(nwgEnc, 1, 1), 256, 0, stream>>>(
      cat, WmT, bm, mrg, NROWS, HIDDEN, 2 * HIDDEN, HIDDEN, 0,
      nullptr, nullptr, nullptr, 0);
  ln_kernel<<<NROWS, 256, 0, stream>>>(mrg, lnw, lnb, nrm);
  // logits = (normed @ Wo + bo) * 0.1 -> d_out f32 (non-temporal stores)
  gemm_bt_kernel<2><<<dim3(nwgOut, 1, 1), 256, 0, stream>>>(
      nrm, WoT, bo, d_out, NROWS, VOCAB, HIDDEN, VOCAB, 0,
      nullptr, nullptr, nullptr, 0);
}

// Round 2
// 1048.734 us; speedup vs baseline: 1.0822x; 1.0294x over previous
//
#include <hip/hip_runtime.h>
#include <hip/hip_bf16.h>
#include <stdint.h>
#include <stdio.h>

// Problem dims (fixed by the reference)
#define T_SEQ  2048
#define BATCH  2
#define NROWS  4096   // B*T
#define EMBED  512
#define HIDDEN 1024
#define VOCAB  32000
#define NCHUNK 32
#define CHLEN  64     // T_SEQ / NCHUNK

typedef __bf16 bf16x8 __attribute__((ext_vector_type(8)));
typedef float  f32x4  __attribute__((ext_vector_type(4)));

__device__ __forceinline__ float b2f(unsigned short h) {
  union { unsigned int u; float f; } v; v.u = ((unsigned int)h) << 16; return v.f;
}
__device__ __forceinline__ unsigned short f2b(float f) {
  union { float f; unsigned int u; } v; v.f = f;
  unsigned int u = v.u;
  u += 0x7fffu + ((u >> 16) & 1u);   // round-to-nearest-even
  return (unsigned short)(u >> 16);
}

// ---------------- gather: emb[row,:] = bf16(E[tokens[row],:]) ----------------
__global__ void gather_kernel(const int* __restrict__ tokens,
                              const float* __restrict__ E,
                              unsigned short* __restrict__ emb) {
  const int row = blockIdx.x;
  const int tok = tokens[row];
  const float2 v = ((const float2*)(E + (size_t)tok * EMBED))[threadIdx.x];
  const uint32_t packed = (uint32_t)f2b(v.x) | ((uint32_t)f2b(v.y) << 16);
  ((uint32_t*)(emb + (size_t)row * EMBED))[threadIdx.x] = packed;  // 256 thr * 2 bf16
}

// ------------- prefix mean, 3-pass chunked scan -------------
__global__ void scan_sum_kernel(const unsigned short* __restrict__ emb,
                                float* __restrict__ csum) {
  const int bc = blockIdx.x;                 // b*NCHUNK + c
  const int d  = threadIdx.x;
  const unsigned short* e = emb + ((size_t)bc * CHLEN) * EMBED + d;
  float s = 0.f;
  #pragma unroll 8
  for (int i = 0; i < CHLEN; ++i) s += b2f(e[(size_t)i * EMBED]);
  csum[(size_t)bc * EMBED + d] = s;
}

__global__ void scan_excl_kernel(float* __restrict__ csum) {
  const int b = blockIdx.x;
  const int d = threadIdx.x;
  float run = 0.f;
  for (int c = 0; c < NCHUNK; ++c) {
    const size_t idx = ((size_t)b * NCHUNK + c) * EMBED + d;
    const float v = csum[idx];
    csum[idx] = run;
    run += v;
  }
}

__global__ void scan_emit_kernel(const unsigned short* __restrict__ emb,
                                 const float* __restrict__ csum,
                                 unsigned short* __restrict__ hist) {
  const int bc = blockIdx.x;                 // b*NCHUNK + c
  const int c  = bc & (NCHUNK - 1);
  const int d  = threadIdx.x;
  const unsigned short* e = emb  + ((size_t)bc * CHLEN) * EMBED + d;
  unsigned short*       h = hist + ((size_t)bc * CHLEN) * EMBED + d;
  float sum = csum[(size_t)bc * EMBED + d];  // exclusive prefix
  #pragma unroll 8
  for (int i = 0; i < CHLEN; ++i) {
    const int t = c * CHLEN + i;
    h[(size_t)i * EMBED] = (t == 0) ? e[0] : f2b(sum / (float)t);
    sum += b2f(e[(size_t)i * EMBED]);
  }
}

// ------------- transpose + f32->bf16 cast: out[C,R] = bf16(in[R,C]^T) -------------
__global__ void transpose_cast_kernel(const float* __restrict__ in,
                                      unsigned short* __restrict__ out,
                                      int R, int C) {
  __shared__ float tile[32][33];
  const int tx = threadIdx.x & 31;
  const int ty = threadIdx.x >> 5;
  const int r0 = blockIdx.y * 32, c0 = blockIdx.x * 32;
  #pragma unroll
  for (int i = 0; i < 32; i += 8)
    tile[ty + i][tx] = in[(size_t)(r0 + ty + i) * C + (c0 + tx)];
  __syncthreads();
  #pragma unroll
  for (int i = 0; i < 32; i += 8)
    out[(size_t)(c0 + ty + i) * R + (r0 + tx)] = f2b(tile[tx][ty + i]);
}

__device__ __forceinline__ void async16(unsigned short* lds, const unsigned short* g) {
  __builtin_amdgcn_global_load_lds(
      (const __attribute__((address_space(1))) void*)g,
      (__attribute__((address_space(3))) void*)lds, 16, 0, 0);
}

// ---------------- 128x128 MFMA GEMM (encode / merge) ----------------
// MODE 0: relu -> bf16 ; MODE 1: relu -> f32 ; MODE 2: (x+bias)*0.1 -> f32
#define BM 128
#define BN 128
#define BK 32

template<int MODE>
__global__ __launch_bounds__(256) void gemm_bt_kernel(
    const unsigned short* __restrict__ A,
    const unsigned short* __restrict__ BT,
    const float* __restrict__ bias,
    void* __restrict__ out, int M, int N, int K, int ldOut, int colOff,
    const unsigned short* __restrict__ A2,
    const unsigned short* __restrict__ BT2,
    const float* __restrict__ bias2, int colOff2) {
  __shared__ unsigned short As[BM * BK];
  __shared__ unsigned short Bs[BN * BK];

  const unsigned short* Ap = A;
  const unsigned short* Bp = BT;
  const float*          bp = bias;
  int                   co = colOff;
  if (blockIdx.z) { Ap = A2; Bp = BT2; bp = bias2; co = colOff2; }

  int wg = blockIdx.x;
  {
    const int nwg = gridDim.x;
    const int xcd = wg & 7, loc = wg >> 3;
    const int q = nwg >> 3, r = nwg & 7;
    wg = (xcd < r ? xcd * (q + 1) : r * (q + 1) + (xcd - r) * q) + loc;
  }
  const int nmb = M / BM;
  const int mb  = wg % nmb;
  const int nb  = wg / nmb;
  const int m0  = mb * BM;
  const int n0  = nb * BN;

  const int tid  = threadIdx.x;
  const int wave = tid >> 6;
  const int lane = tid & 63;
  const int wm = (wave & 1) * 64;
  const int wn = (wave >> 1) * 64;

  const int srow = (wave << 5) + (lane >> 2);
  const int scol = (lane & 3) << 3;
  const unsigned short* aSrc = Ap + (size_t)(m0 + srow) * K + scol;
  const unsigned short* bSrc = Bp + (size_t)(n0 + srow) * K + scol;
  unsigned short* aDst = As + (wave << 5) * BK;
  unsigned short* bDst = Bs + (wave << 5) * BK;

  f32x4 acc[4][4];
  #pragma unroll
  for (int i = 0; i < 4; ++i)
    #pragma unroll
    for (int j = 0; j < 4; ++j)
      acc[i][j] = (f32x4){0.f, 0.f, 0.f, 0.f};

  const int q = lane >> 4;
  const int r = lane & 15;

  for (int k0 = 0; k0 < K; k0 += BK) {
    __syncthreads();
    async16(aDst,           aSrc);
    async16(aDst + 16 * BK, aSrc + 16 * (size_t)K);
    async16(bDst,           bSrc);
    async16(bDst + 16 * BK, bSrc + 16 * (size_t)K);
    aSrc += BK; bSrc += BK;
    __syncthreads();

    bf16x8 af[4], bfr[4];
    #pragma unroll
    for (int mi = 0; mi < 4; ++mi)
      af[mi] = *(const bf16x8*)&As[(wm + mi * 16 + r) * BK + (q << 3)];
    #pragma unroll
    for (int ni = 0; ni < 4; ++ni)
      bfr[ni] = *(const bf16x8*)&Bs[(wn + ni * 16 + r) * BK + (q << 3)];
    #pragma unroll
    for (int mi = 0; mi < 4; ++mi)
      #pragma unroll
      for (int ni = 0; ni < 4; ++ni)
        acc[mi][ni] = __builtin_amdgcn_mfma_f32_16x16x32_bf16(
            af[mi], bfr[ni], acc[mi][ni], 0, 0, 0);
  }

  #pragma unroll
  for (int ni = 0; ni < 4; ++ni) {
    const int col = n0 + wn + ni * 16 + r;
    const float bv = bp[col];
    #pragma unroll
    for (int mi = 0; mi < 4; ++mi) {
      #pragma unroll
      for (int e = 0; e < 4; ++e) {
        const int row = m0 + wm + mi * 16 + (q << 2) + e;
        float v = acc[mi][ni][e] + bv;
        if (MODE == 0 || MODE == 1) v = fmaxf(v, 0.f);
        if (MODE == 2) v *= 0.1f;
        const size_t idx = (size_t)row * ldOut + co + col;
        if (MODE == 0) ((unsigned short*)out)[idx] = f2b(v);
        else           ((float*)out)[idx] = v;
      }
    }
  }
}

// ============ 256x256 8-wave deep-pipelined GEMM (logits / MODE2) ============
// BK=64, 2 LDS buffers (128 KiB), 4 phases per K-tile, region-retirement
// staging schedule, counted vmcnt(6) (never 0 in steady state), T2 XOR-swizzle
// (linear global_load_lds dest + inverse-swizzled global source, rule 21),
// T5 setprio around MFMA clusters.
//
// Staging schedule for K-tile u (buffer bu=u&1):
//   p1: ds A[m0-3]+B[n0-1]; stage B1(u+1)->buf[1-bu]   (that buf fully dead)
//   p2: ds A[m4-7]                                     (A regions retire here)
//   p3: ds B[n2-3];        stage A0(u+2)->buf[bu]      (A dead since p2 barrier)
//   p4: stage A1(u+2),B0(u+2)->buf[bu] (B dead since p3 barrier); vmcnt(6)
// vmcnt(6) = 3 newer half-tiles in flight -> waits exactly tile u+1 resident.

#define BAR() do {                            \
    asm volatile("" ::: "memory");            \
    __builtin_amdgcn_sched_barrier(0);        \
    __builtin_amdgcn_s_barrier();             \
    __builtin_amdgcn_sched_barrier(0);        \
    asm volatile("" ::: "memory");            \
  } while (0)

__global__ __launch_bounds__(512, 2) void gemm256_out_kernel(
    const unsigned short* __restrict__ A,
    const unsigned short* __restrict__ BT,
    const float* __restrict__ bias,
    float* __restrict__ out, int M, int N, int K, int ldOut) {
  // [buf][mat A=0/B=1][half][128 rows * 64 cols]
  __shared__ unsigned short lds[2][2][2][8192];

  // bijective XCD chunk swizzle + m-fastest (B-panel reuse on one XCD's L2)
  int wg = blockIdx.x;
  {
    const int nwg = gridDim.x;
    const int xcd = wg & 7, loc = wg >> 3;
    const int q8 = nwg >> 3, r8 = nwg & 7;
    wg = (xcd < r8 ? xcd * (q8 + 1) : r8 * (q8 + 1) + (xcd - r8) * q8) + loc;
  }
  const int nmb = M >> 8;
  const int mb = wg % nmb, nb = wg / nmb;
  const int m0 = mb << 8, n0 = nb << 8;

  const int tid  = threadIdx.x;
  const int wave = tid >> 6, lane = tid & 63;
  const int wr = wave >> 2, wc = wave & 3;     // 2x4 wave grid; per-wave out 128x64
  const int q = lane >> 4, r = lane & 15, rr = lane & 7;

  // staging: per half-tile (128 rows x 64 k) each wave issues 2 global_load_lds.
  // LDS dest is linear (base + lane*16B); the XOR swizzle is applied by
  // permuting the GLOBAL source column-slot: slot = (lane&7) ^ (lane>>3).
  const int srow = (wave << 4) + (lane >> 3);          // row within half
  const int scol = ((lane & 7) ^ (lane >> 3)) << 3;    // element col (slot*8)
  const unsigned short* aB = A  + (size_t)(m0 + srow) * K + scol;
  const unsigned short* bB = BT + (size_t)(n0 + srow) * K + scol;

  const int NTt = K >> 6;  // K-tiles of 64

  auto stage = [&](int matB, int h, int tb, int kt) {
    unsigned short* d = &lds[tb][matB][h][wave << 10];
    const unsigned short* s =
        (matB ? bB : aB) + (size_t)h * 128 * K + ((size_t)kt << 6);
    async16(d, s);
    async16(d + 512, s + ((size_t)K << 3));
  };

  // swizzled LDS reads: byte row stride 128B = 8 slots of 16B; slot ^= row&7.
  // A-frag row = mi*16 + r  (row&7 == r&7 == rr); same for B.
  auto ldA = [&](int tb, int mi, int ks) {
    return *(const bf16x8*)&lds[tb][0][wr]
        [(mi * 16 + r) * 64 + ((((ks << 2) | q) ^ rr) << 3)];
  };
  auto ldB = [&](int tb, int ni, int ks) {
    return *(const bf16x8*)&lds[tb][1][wc >> 1]
        [(((wc & 1) << 6) + ni * 16 + r) * 64 + ((((ks << 2) | q) ^ rr) << 3)];
  };

  f32x4 acc[8][4];
  #pragma unroll
  for (int i = 0; i < 8; ++i)
    #pragma unroll
    for (int j = 0; j < 4; ++j)
      acc[i][j] = (f32x4){0.f, 0.f, 0.f, 0.f};

  bf16x8 afr[8][2], bfr[2][2];

  // prologue: tile 0 complete + A0,A1,B0 of tile 1 -> vmcnt(6) leaves those 3.
  stage(0, 0, 0, 0); stage(0, 1, 0, 0); stage(1, 0, 0, 0); stage(1, 1, 0, 0);
  if (NTt > 1) {
    stage(0, 0, 1, 1); stage(0, 1, 1, 1); stage(1, 0, 1, 1);
    asm volatile("s_waitcnt vmcnt(6)" ::: "memory");
  } else {
    asm volatile("s_waitcnt vmcnt(0)" ::: "memory");
  }
  BAR();

#define TILE(U, BU) do {                                                       \
    const int u_ = (U);                                                        \
    /* ---- p1: A[m0-3], B[n0-1]; stage B1(u+1) ---- */                        \
    _Pragma("unroll")                                                          \
    for (int mi = 0; mi < 4; ++mi) {                                           \
      afr[mi][0] = ldA(BU, mi, 0); afr[mi][1] = ldA(BU, mi, 1);                \
    }                                                                          \
    _Pragma("unroll")                                                          \
    for (int nj = 0; nj < 2; ++nj) {                                           \
      bfr[nj][0] = ldB(BU, nj, 0); bfr[nj][1] = ldB(BU, nj, 1);                \
    }                                                                          \
    if (u_ + 1 < NTt) stage(1, 1, 1 - (BU), u_ + 1);                           \
    __builtin_amdgcn_s_setprio(1);                                             \
    _Pragma("unroll")                                                          \
    for (int mi = 0; mi < 4; ++mi)                                             \
      _Pragma("unroll")                                                        \
      for (int nj = 0; nj < 2; ++nj) {                                         \
        acc[mi][nj] = __builtin_amdgcn_mfma_f32_16x16x32_bf16(                 \
            afr[mi][0], bfr[nj][0], acc[mi][nj], 0, 0, 0);                     \
        acc[mi][nj] = __builtin_amdgcn_mfma_f32_16x16x32_bf16(                 \
            afr[mi][1], bfr[nj][1], acc[mi][nj], 0, 0, 0);                     \
      }                                                                        \
    __builtin_amdgcn_s_setprio(0);                                             \
    BAR();                                                                     \
    /* ---- p2: A[m4-7] (A regions retire) ---- */                             \
    _Pragma("unroll")                                                          \
    for (int mi = 4; mi < 8; ++mi) {                                           \
      afr[mi][0] = ldA(BU, mi, 0); afr[mi][1] = ldA(BU, mi, 1);                \
    }                                                                          \
    __builtin_amdgcn_s_setprio(1);                                             \
    _Pragma("unroll")                                                          \
    for (int mi = 4; mi < 8; ++mi)                                             \
      _Pragma("unroll")                                                        \
      for (int nj = 0; nj < 2; ++nj) {                                         \
        acc[mi][nj] = __builtin_amdgcn_mfma_f32_16x16x32_bf16(                 \
            afr[mi][0], bfr[nj][0], acc[mi][nj], 0, 0, 0);                     \
        acc[mi][nj] = __builtin_amdgcn_mfma_f32_16x16x32_bf16(                 \
            afr[mi][1], bfr[nj][1], acc[mi][nj], 0, 0, 0);                     \
      }                                                                        \
    __builtin_amdgcn_s_setprio(0);                                             \
    BAR();                                                                     \
    /* ---- p3: B[n2-3]; stage A0(u+2) (A dead) ---- */                        \
    _Pragma("unroll")                                                          \
    for (int nj = 0; nj < 2; ++nj) {                                           \
      bfr[nj][0] = ldB(BU, 2 + nj, 0); bfr[nj][1] = ldB(BU, 2 + nj, 1);        \
    }                                                                          \
    if (u_ + 2 < NTt) stage(0, 0, BU, u_ + 2);                                 \
    __builtin_amdgcn_s_setprio(1);                                             \
    _Pragma("unroll")                                                          \
    for (int mi = 0; mi < 4; ++mi)                                             \
      _Pragma("unroll")                                                        \
      for (int nj = 0; nj < 2; ++nj) {                                         \
        acc[mi][2 + nj] = __builtin_amdgcn_mfma_f32_16x16x32_bf16(             \
            afr[mi][0], bfr[nj][0], acc[mi][2 + nj], 0, 0, 0);                 \
        acc[mi][2 + nj] = __builtin_amdgcn_mfma_f32_16x16x32_bf16(             \
            afr[mi][1], bfr[nj][1], acc[mi][2 + nj], 0, 0, 0);                 \
      }                                                                        \
    __builtin_amdgcn_s_setprio(0);                                             \
    BAR();                                                                     \
    /* ---- p4: stage A1,B0(u+2) (B dead); counted vmcnt ---- */               \
    if (u_ + 2 < NTt) { stage(0, 1, BU, u_ + 2); stage(1, 0, BU, u_ + 2); }    \
    __builtin_amdgcn_s_setprio(1);                                             \
    _Pragma("unroll")                                                          \
    for (int mi = 4; mi < 8; ++mi)                                             \
      _Pragma("unroll")                                                        \
      for (int nj = 0; nj < 2; ++nj) {                                         \
        acc[mi][2 + nj] = __builtin_amdgcn_mfma_f32_16x16x32_bf16(             \
            afr[mi][0], bfr[nj][0], acc[mi][2 + nj], 0, 0, 0);                 \
        acc[mi][2 + nj] = __builtin_amdgcn_mfma_f32_16x16x32_bf16(             \
            afr[mi][1], bfr[nj][1], acc[mi][2 + nj], 0, 0, 0);                 \
      }                                                                        \
    __builtin_amdgcn_s_setprio(0);                                             \
    if (u_ + 2 < NTt) asm volatile("s_waitcnt vmcnt(6)" ::: "memory");         \
    else              asm volatile("s_waitcnt vmcnt(0)" ::: "memory");         \
    BAR();                                                                     \
  } while (0)

  for (int u = 0; u < NTt; u += 2) {
    TILE(u, 0);
    TILE(u + 1, 1);
  }
#undef TILE

  // epilogue: (x + bias) * 0.1 -> f32, normal stores (L2 write-combines)
  #pragma unroll
  for (int ni = 0; ni < 4; ++ni) {
    const int col = n0 + (wc << 6) + ni * 16 + r;
    const float bv = bias[col];
    #pragma unroll
    for (int mi = 0; mi < 8; ++mi) {
      const int row = m0 + (wr << 7) + mi * 16 + (q << 2);
      #pragma unroll
      for (int e = 0; e < 4; ++e)
        out[(size_t)(row + e) * ldOut + col] = (acc[mi][ni][e] + bv) * 0.1f;
    }
  }
}

// ---------------- LayerNorm over last dim (1024), f32 in -> bf16 out ----------------
__global__ void ln_kernel(const float* __restrict__ merged,
                          const float* __restrict__ lnw,
                          const float* __restrict__ lnb,
                          unsigned short* __restrict__ normed) {
  const int row = blockIdx.x;
  const float4 v = ((const float4*)(merged + (size_t)row * HIDDEN))[threadIdx.x];
  float s  = v.x + v.y + v.z + v.w;
  float ss = v.x * v.x + v.y * v.y + v.z * v.z + v.w * v.w;
  #pragma unroll
  for (int off = 32; off > 0; off >>= 1) {
    s  += __shfl_down(s, off, 64);
    ss += __shfl_down(ss, off, 64);
  }
  __shared__ float red[8];
  const int wvi = threadIdx.x >> 6;
  if ((threadIdx.x & 63) == 0) { red[wvi] = s; red[4 + wvi] = ss; }
  __syncthreads();
  s  = red[0] + red[1] + red[2] + red[3];
  ss = red[4] + red[5] + red[6] + red[7];
  const float mu  = s * (1.0f / HIDDEN);
  const float var = ss * (1.0f / HIDDEN) - mu * mu;
  const float rs  = rsqrtf(var + 1e-5f);
  const float4 w4 = ((const float4*)lnw)[threadIdx.x];
  const float4 b4 = ((const float4*)lnb)[threadIdx.x];
  ushort4 o;
  o.x = f2b((v.x - mu) * rs * w4.x + b4.x);
  o.y = f2b((v.y - mu) * rs * w4.y + b4.y);
  o.z = f2b((v.z - mu) * rs * w4.z + b4.z);
  o.w = f2b((v.w - mu) * rs * w4.w + b4.w);
  ((ushort4*)(normed + (size_t)row * HIDDEN))[threadIdx.x] = o;
}

extern "C" void kernel_launch(void* const* d_in, const int* in_sizes, int n_in,
                              void* d_out, int out_size, void* d_ws, size_t ws_size,
                              hipStream_t stream) {
  const int*   tokens = (const int*)d_in[0];
  const float* E      = (const float*)d_in[1];
  const float* Wc     = (const float*)d_in[2];
  const float* bc     = (const float*)d_in[3];
  const float* Wh     = (const float*)d_in[4];
  const float* bh     = (const float*)d_in[5];
  const float* Wm     = (const float*)d_in[6];
  const float* bm     = (const float*)d_in[7];
  const float* Wo     = (const float*)d_in[8];
  const float* bo     = (const float*)d_in[9];
  const float* lnw    = (const float*)d_in[10];
  const float* lnb    = (const float*)d_in[11];

  char* p = (char*)d_ws;
  unsigned short* WcT  = (unsigned short*)p; p += (size_t)HIDDEN * EMBED * 2;
  unsigned short* WhT  = (unsigned short*)p; p += (size_t)HIDDEN * EMBED * 2;
  unsigned short* WmT  = (unsigned short*)p; p += (size_t)HIDDEN * (2 * HIDDEN) * 2;
  unsigned short* WoT  = (unsigned short*)p; p += (size_t)VOCAB * HIDDEN * 2;
  unsigned short* emb  = (unsigned short*)p; p += (size_t)NROWS * EMBED * 2;
  unsigned short* hist = (unsigned short*)p; p += (size_t)NROWS * EMBED * 2;
  unsigned short* cat  = (unsigned short*)p; p += (size_t)NROWS * (2 * HIDDEN) * 2;
  float*          mrg  = (float*)p;          p += (size_t)NROWS * HIDDEN * 4;
  unsigned short* nrm  = (unsigned short*)p; p += (size_t)NROWS * HIDDEN * 2;
  float*          csum = (float*)p;          p += (size_t)BATCH * NCHUNK * EMBED * 4;
  if ((size_t)(p - (char*)d_ws) > ws_size)
    fprintf(stderr, "WS TOO SMALL: need %zu have %zu\n", (size_t)(p - (char*)d_ws), ws_size);

  transpose_cast_kernel<<<dim3(HIDDEN / 32, EMBED / 32), 256, 0, stream>>>(Wc, WcT, EMBED, HIDDEN);
  transpose_cast_kernel<<<dim3(HIDDEN / 32, EMBED / 32), 256, 0, stream>>>(Wh, WhT, EMBED, HIDDEN);
  transpose_cast_kernel<<<dim3(HIDDEN / 32, (2 * HIDDEN) / 32), 256, 0, stream>>>(Wm, WmT, 2 * HIDDEN, HIDDEN);
  transpose_cast_kernel<<<dim3(VOCAB / 32, HIDDEN / 32), 256, 0, stream>>>(Wo, WoT, HIDDEN, VOCAB);

  gather_kernel<<<NROWS, 256, 0, stream>>>(tokens, E, emb);
  scan_sum_kernel <<<BATCH * NCHUNK, EMBED, 0, stream>>>(emb, csum);
  scan_excl_kernel<<<BATCH, EMBED, 0, stream>>>(csum);
  scan_emit_kernel<<<BATCH * NCHUNK, EMBED, 0, stream>>>(emb, csum, hist);

  const int nwgEnc = (NROWS / BM) * (HIDDEN / BN);   // 256 tiles per slice

  // cur_enc / hist_enc fused into one launch (z=2) -> concatenated [4096, 2048] bf16
  gemm_bt_kernel<0><<<dim3(nwgEnc, 1, 2), 256, 0, stream>>>(
      emb, WcT, bc, cat, NROWS, HIDDEN, EMBED, 2 * HIDDEN, 0,
      hist, WhT, bh, HIDDEN);
  // merged = relu(cat @ Wm + bm), kept f32 for LN accuracy
  gemm_bt_kernel<1><<<dim3(nwgEnc, 1, 1), 256, 0, stream>>>(
      cat, WmT, bm, mrg, NROWS, HIDDEN, 2 * HIDDEN, HIDDEN, 0,
      nullptr, nullptr, nullptr, 0);
  ln_kernel<<<NROWS, 256, 0, stream>>>(mrg, lnw, lnb, nrm);

  // logits = (normed @ Wo + bo) * 0.1 -> d_out f32, 256^2 8-phase kernel
  const int nwgOut = (NROWS / 256) * (VOCAB / 256);  // 16 * 125 = 2000
  gemm256_out_kernel<<<dim3(nwgOut), 512, 0, stream>>>(
      nrm, WoT, bo, (float*)d_out, NROWS, VOCAB, HIDDEN, VOCAB);
}

// Round 3
// 986.209 us; speedup vs baseline: 1.1509x; 1.0634x over previous
//
#include <hip/hip_runtime.h>
#include <hip/hip_bf16.h>
#include <stdint.h>
#include <stdio.h>

// Problem dims (fixed by the reference)
#define T_SEQ  2048
#define BATCH  2
#define NROWS  4096   // B*T
#define EMBED  512
#define HIDDEN 1024
#define VOCAB  32000
#define NCHUNK 32
#define CHLEN  64     // T_SEQ / NCHUNK

typedef __bf16 bf16x8 __attribute__((ext_vector_type(8)));
typedef float  f32x4  __attribute__((ext_vector_type(4)));

__device__ __forceinline__ float b2f(unsigned short h) {
  union { unsigned int u; float f; } v; v.u = ((unsigned int)h) << 16; return v.f;
}
__device__ __forceinline__ unsigned short f2b(float f) {
  union { float f; unsigned int u; } v; v.f = f;
  unsigned int u = v.u;
  u += 0x7fffu + ((u >> 16) & 1u);   // round-to-nearest-even
  return (unsigned short)(u >> 16);
}

// -------- fused gather + chunk-sum: emb = bf16(E[tok]); csum[bc] = Σ chunk --------
__global__ void gather_sum_kernel(const int* __restrict__ tokens,
                                  const float* __restrict__ E,
                                  unsigned short* __restrict__ emb,
                                  float* __restrict__ csum) {
  const int bc = blockIdx.x;               // b*NCHUNK + c  (64 blocks)
  const int d  = threadIdx.x;              // 0..511
  __shared__ int tok[CHLEN];
  if (d < CHLEN) tok[d] = tokens[bc * CHLEN + d];
  __syncthreads();
  float s = 0.f;
  unsigned short* eo = emb + ((size_t)bc * CHLEN) * EMBED + d;
  #pragma unroll 4
  for (int i = 0; i < CHLEN; ++i) {
    const float v = E[(size_t)tok[i] * EMBED + d];
    const unsigned short h = f2b(v);
    eo[(size_t)i * EMBED] = h;
    s += b2f(h);                           // bf16-rounded accumulation (matches emit)
  }
  csum[(size_t)bc * EMBED + d] = s;
}

__global__ void scan_excl_kernel(float* __restrict__ csum) {
  const int b = blockIdx.x;
  const int d = threadIdx.x;
  float run = 0.f;
  for (int c = 0; c < NCHUNK; ++c) {
    const size_t idx = ((size_t)b * NCHUNK + c) * EMBED + d;
    const float v = csum[idx];
    csum[idx] = run;
    run += v;
  }
}

__global__ void scan_emit_kernel(const unsigned short* __restrict__ emb,
                                 const float* __restrict__ csum,
                                 unsigned short* __restrict__ hist) {
  const int bc = blockIdx.x;                 // b*NCHUNK + c
  const int c  = bc & (NCHUNK - 1);
  const int d  = threadIdx.x;
  const unsigned short* e = emb  + ((size_t)bc * CHLEN) * EMBED + d;
  unsigned short*       h = hist + ((size_t)bc * CHLEN) * EMBED + d;
  float sum = csum[(size_t)bc * EMBED + d];  // exclusive prefix
  #pragma unroll 8
  for (int i = 0; i < CHLEN; ++i) {
    const int t = c * CHLEN + i;
    h[(size_t)i * EMBED] = (t == 0) ? e[0] : f2b(sum / (float)t);
    sum += b2f(e[(size_t)i * EMBED]);
  }
}

// -------- single-launch transpose+cast for all 4 weights, 64x64 f32 tiles --------
// loads float4 (256B/quarter-wave), stores ushort4 (128B/quarter-wave).
__global__ __launch_bounds__(256) void transpose_all_kernel(
    const float* __restrict__ Wc, const float* __restrict__ Wh,
    const float* __restrict__ Wm, const float* __restrict__ Wo,
    unsigned short* __restrict__ WcT, unsigned short* __restrict__ WhT,
    unsigned short* __restrict__ WmT, unsigned short* __restrict__ WoT) {
  const int id = blockIdx.x;
  const float* in; unsigned short* out; int R, C, t;
  if (id < 128)      { in = Wc; out = WcT; R = 512;  C = 1024;  t = id; }
  else if (id < 256) { in = Wh; out = WhT; R = 512;  C = 1024;  t = id - 128; }
  else if (id < 768) { in = Wm; out = WmT; R = 2048; C = 1024;  t = id - 256; }
  else               { in = Wo; out = WoT; R = 1024; C = 32000; t = id - 768; }
  const int tilesX = C >> 6;
  const int r0 = (t / tilesX) << 6, c0 = (t % tilesX) << 6;

  __shared__ float tile[64][65];             // 65: col-reads conflict-free
  const int tid = threadIdx.x;
  #pragma unroll
  for (int p = 0; p < 4; ++p) {
    const int u = tid + p * 256;             // 1024 float4 units
    const int row = u >> 4, cq = (u & 15) << 2;
    const float4 v = *(const float4*)&in[(size_t)(r0 + row) * C + c0 + cq];
    tile[row][cq + 0] = v.x; tile[row][cq + 1] = v.y;
    tile[row][cq + 2] = v.z; tile[row][cq + 3] = v.w;
  }
  __syncthreads();
  #pragma unroll
  for (int p = 0; p < 4; ++p) {
    const int u = tid + p * 256;             // 1024 ushort4 units
    const int oc = u >> 4, org = (u & 15) << 2;
    ushort4 o;
    o.x = f2b(tile[org + 0][oc]); o.y = f2b(tile[org + 1][oc]);
    o.z = f2b(tile[org + 2][oc]); o.w = f2b(tile[org + 3][oc]);
    *(ushort4*)&out[(size_t)(c0 + oc) * R + r0 + org] = o;
  }
}

__device__ __forceinline__ void async16(unsigned short* lds, const unsigned short* g) {
  __builtin_amdgcn_global_load_lds(
      (const __attribute__((address_space(1))) void*)g,
      (__attribute__((address_space(3))) void*)lds, 16, 0, 0);
}

// ---------------- 128x128 MFMA GEMM (encode / merge) ----------------
// MODE 0: relu -> bf16 ; MODE 1: relu -> f32
#define BM 128
#define BN 128
#define BK 32

template<int MODE>
__global__ __launch_bounds__(256) void gemm_bt_kernel(
    const unsigned short* __restrict__ A,
    const unsigned short* __restrict__ BT,
    const float* __restrict__ bias,
    void* __restrict__ out, int M, int N, int K, int ldOut, int colOff,
    const unsigned short* __restrict__ A2,
    const unsigned short* __restrict__ BT2,
    const float* __restrict__ bias2, int colOff2) {
  __shared__ unsigned short As[BM * BK];
  __shared__ unsigned short Bs[BN * BK];

  const unsigned short* Ap = A;
  const unsigned short* Bp = BT;
  const float*          bp = bias;
  int                   co = colOff;
  if (blockIdx.z) { Ap = A2; Bp = BT2; bp = bias2; co = colOff2; }

  int wg = blockIdx.x;
  {
    const int nwg = gridDim.x;
    const int xcd = wg & 7, loc = wg >> 3;
    const int q = nwg >> 3, r = nwg & 7;
    wg = (xcd < r ? xcd * (q + 1) : r * (q + 1) + (xcd - r) * q) + loc;
  }
  const int nmb = M / BM;
  const int mb  = wg % nmb;
  const int nb  = wg / nmb;
  const int m0  = mb * BM;
  const int n0  = nb * BN;

  const int tid  = threadIdx.x;
  const int wave = tid >> 6;
  const int lane = tid & 63;
  const int wm = (wave & 1) * 64;
  const int wn = (wave >> 1) * 64;

  const int srow = (wave << 5) + (lane >> 2);
  const int scol = (lane & 3) << 3;
  const unsigned short* aSrc = Ap + (size_t)(m0 + srow) * K + scol;
  const unsigned short* bSrc = Bp + (size_t)(n0 + srow) * K + scol;
  unsigned short* aDst = As + (wave << 5) * BK;
  unsigned short* bDst = Bs + (wave << 5) * BK;

  f32x4 acc[4][4];
  #pragma unroll
  for (int i = 0; i < 4; ++i)
    #pragma unroll
    for (int j = 0; j < 4; ++j)
      acc[i][j] = (f32x4){0.f, 0.f, 0.f, 0.f};

  const int q = lane >> 4;
  const int r = lane & 15;

  for (int k0 = 0; k0 < K; k0 += BK) {
    __syncthreads();
    async16(aDst,           aSrc);
    async16(aDst + 16 * BK, aSrc + 16 * (size_t)K);
    async16(bDst,           bSrc);
    async16(bDst + 16 * BK, bSrc + 16 * (size_t)K);
    aSrc += BK; bSrc += BK;
    __syncthreads();

    bf16x8 af[4], bfr[4];
    #pragma unroll
    for (int mi = 0; mi < 4; ++mi)
      af[mi] = *(const bf16x8*)&As[(wm + mi * 16 + r) * BK + (q << 3)];
    #pragma unroll
    for (int ni = 0; ni < 4; ++ni)
      bfr[ni] = *(const bf16x8*)&Bs[(wn + ni * 16 + r) * BK + (q << 3)];
    #pragma unroll
    for (int mi = 0; mi < 4; ++mi)
      #pragma unroll
      for (int ni = 0; ni < 4; ++ni)
        acc[mi][ni] = __builtin_amdgcn_mfma_f32_16x16x32_bf16(
            af[mi], bfr[ni], acc[mi][ni], 0, 0, 0);
  }

  #pragma unroll
  for (int ni = 0; ni < 4; ++ni) {
    const int col = n0 + wn + ni * 16 + r;
    const float bv = bp[col];
    #pragma unroll
    for (int mi = 0; mi < 4; ++mi) {
      #pragma unroll
      for (int e = 0; e < 4; ++e) {
        const int row = m0 + wm + mi * 16 + (q << 2) + e;
        float v = fmaxf(acc[mi][ni][e] + bv, 0.f);
        const size_t idx = (size_t)row * ldOut + co + col;
        if (MODE == 0) ((unsigned short*)out)[idx] = f2b(v);
        else           ((float*)out)[idx] = v;
      }
    }
  }
}

// ============ 256x256 8-wave deep-pipelined GEMM (logits) ============
// Main-loop sync structure UNCHANGED from round 2 (verified race-free, 0 bank
// conflicts). New: LDS-coalesced epilogue — acc -> LDS (2-way-max swizzle) ->
// f32x4 read-back -> global_store_dwordx4 in 1KB contiguous runs per wave
// (full 128B lines, no read-for-ownership RMW).

#define BAR() do {                            \
    asm volatile("" ::: "memory");            \
    __builtin_amdgcn_sched_barrier(0);        \
    __builtin_amdgcn_s_barrier();             \
    __builtin_amdgcn_sched_barrier(0);        \
    asm volatile("" ::: "memory");            \
  } while (0)

__global__ __launch_bounds__(512, 2) void gemm256_out_kernel(
    const unsigned short* __restrict__ A,
    const unsigned short* __restrict__ BT,
    const float* __restrict__ bias,
    float* __restrict__ out, int M, int N, int K, int ldOut) {
  // [buf][mat A=0/B=1][half][128 rows * 64 cols]
  __shared__ unsigned short lds[2][2][2][8192];

  int wg = blockIdx.x;
  {
    const int nwg = gridDim.x;
    const int xcd = wg & 7, loc = wg >> 3;
    const int q8 = nwg >> 3, r8 = nwg & 7;
    wg = (xcd < r8 ? xcd * (q8 + 1) : r8 * (q8 + 1) + (xcd - r8) * q8) + loc;
  }
  const int nmb = M >> 8;
  const int mb = wg % nmb, nb = wg / nmb;
  const int m0 = mb << 8, n0 = nb << 8;

  const int tid  = threadIdx.x;
  const int wave = tid >> 6, lane = tid & 63;
  const int wr = wave >> 2, wc = wave & 3;     // 2x4 wave grid; per-wave out 128x64
  const int q = lane >> 4, r = lane & 15, rr = lane & 7;

  const int srow = (wave << 4) + (lane >> 3);          // row within half
  const int scol = ((lane & 7) ^ (lane >> 3)) << 3;    // inverse-swizzled src col
  const unsigned short* aB = A  + (size_t)(m0 + srow) * K + scol;
  const unsigned short* bB = BT + (size_t)(n0 + srow) * K + scol;

  const int NTt = K >> 6;  // K-tiles of 64

  auto stage = [&](int matB, int h, int tb, int kt) {
    unsigned short* d = &lds[tb][matB][h][wave << 10];
    const unsigned short* s =
        (matB ? bB : aB) + (size_t)h * 128 * K + ((size_t)kt << 6);
    async16(d, s);
    async16(d + 512, s + ((size_t)K << 3));
  };

  auto ldA = [&](int tb, int mi, int ks) {
    return *(const bf16x8*)&lds[tb][0][wr]
        [(mi * 16 + r) * 64 + ((((ks << 2) | q) ^ rr) << 3)];
  };
  auto ldB = [&](int tb, int ni, int ks) {
    return *(const bf16x8*)&lds[tb][1][wc >> 1]
        [(((wc & 1) << 6) + ni * 16 + r) * 64 + ((((ks << 2) | q) ^ rr) << 3)];
  };

  f32x4 acc[8][4];
  #pragma unroll
  for (int i = 0; i < 8; ++i)
    #pragma unroll
    for (int j = 0; j < 4; ++j)
      acc[i][j] = (f32x4){0.f, 0.f, 0.f, 0.f};

  bf16x8 afr[8][2], bfr[2][2];

  // prologue: tile 0 complete + A0,A1,B0 of tile 1 -> vmcnt(6) leaves those 3.
  stage(0, 0, 0, 0); stage(0, 1, 0, 0); stage(1, 0, 0, 0); stage(1, 1, 0, 0);
  if (NTt > 1) {
    stage(0, 0, 1, 1); stage(0, 1, 1, 1); stage(1, 0, 1, 1);
    asm volatile("s_waitcnt vmcnt(6)" ::: "memory");
  } else {
    asm volatile("s_waitcnt vmcnt(0)" ::: "memory");
  }
  BAR();

#define TILE(U, BU) do {                                                       \
    const int u_ = (U);                                                        \
    /* ---- p1: A[m0-3], B[n0-1]; stage B1(u+1) ---- */                        \
    _Pragma("unroll")                                                          \
    for (int mi = 0; mi < 4; ++mi) {                                           \
      afr[mi][0] = ldA(BU, mi, 0); afr[mi][1] = ldA(BU, mi, 1);                \
    }                                                                          \
    _Pragma("unroll")                                                          \
    for (int nj = 0; nj < 2; ++nj) {                                           \
      bfr[nj][0] = ldB(BU, nj, 0); bfr[nj][1] = ldB(BU, nj, 1);                \
    }                                                                          \
    if (u_ + 1 < NTt) stage(1, 1, 1 - (BU), u_ + 1);                           \
    __builtin_amdgcn_s_setprio(1);                                             \
    _Pragma("unroll")                                                          \
    for (int mi = 0; mi < 4; ++mi)                                             \
      _Pragma("unroll")                                                        \
      for (int nj = 0; nj < 2; ++nj) {                                         \
        acc[mi][nj] = __builtin_amdgcn_mfma_f32_16x16x32_bf16(                 \
            afr[mi][0], bfr[nj][0], acc[mi][nj], 0, 0, 0);                     \
        acc[mi][nj] = __builtin_amdgcn_mfma_f32_16x16x32_bf16(                 \
            afr[mi][1], bfr[nj][1], acc[mi][nj], 0, 0, 0);                     \
      }                                                                        \
    __builtin_amdgcn_s_setprio(0);                                             \
    BAR();                                                                     \
    /* ---- p2: A[m4-7] (A regions retire) ---- */                             \
    _Pragma("unroll")                                                          \
    for (int mi = 4; mi < 8; ++mi) {                                           \
      afr[mi][0] = ldA(BU, mi, 0); afr[mi][1] = ldA(BU, mi, 1);                \
    }                                                                          \
    __builtin_amdgcn_s_setprio(1);                                             \
    _Pragma("unroll")                                                          \
    for (int mi = 4; mi < 8; ++mi)                                             \
      _Pragma("unroll")                                                        \
      for (int nj = 0; nj < 2; ++nj) {                                         \
        acc[mi][nj] = __builtin_amdgcn_mfma_f32_16x16x32_bf16(                 \
            afr[mi][0], bfr[nj][0], acc[mi][nj], 0, 0, 0);                     \
        acc[mi][nj] = __builtin_amdgcn_mfma_f32_16x16x32_bf16(                 \
            afr[mi][1], bfr[nj][1], acc[mi][nj], 0, 0, 0);                     \
      }                                                                        \
    __builtin_amdgcn_s_setprio(0);                                             \
    BAR();                                                                     \
    /* ---- p3: B[n2-3]; stage A0(u+2) (A dead) ---- */                        \
    _Pragma("unroll")                                                          \
    for (int nj = 0; nj < 2; ++nj) {                                           \
      bfr[nj][0] = ldB(BU, 2 + nj, 0); bfr[nj][1] = ldB(BU, 2 + nj, 1);        \
    }                                                                          \
    if (u_ + 2 < NTt) stage(0, 0, BU, u_ + 2);                                 \
    __builtin_amdgcn_s_setprio(1);                                             \
    _Pragma("unroll")                                                          \
    for (int mi = 0; mi < 4; ++mi)                                             \
      _Pragma("unroll")                                                        \
      for (int nj = 0; nj < 2; ++nj) {                                         \
        acc[mi][2 + nj] = __builtin_amdgcn_mfma_f32_16x16x32_bf16(             \
            afr[mi][0], bfr[nj][0], acc[mi][2 + nj], 0, 0, 0);                 \
        acc[mi][2 + nj] = __builtin_amdgcn_mfma_f32_16x16x32_bf16(             \
            afr[mi][1], bfr[nj][1], acc[mi][2 + nj], 0, 0, 0);                 \
      }                                                                        \
    __builtin_amdgcn_s_setprio(0);                                             \
    BAR();                                                                     \
    /* ---- p4: stage A1,B0(u+2) (B dead); counted vmcnt ---- */               \
    if (u_ + 2 < NTt) { stage(0, 1, BU, u_ + 2); stage(1, 0, BU, u_ + 2); }    \
    __builtin_amdgcn_s_setprio(1);                                             \
    _Pragma("unroll")                                                          \
    for (int mi = 4; mi < 8; ++mi)                                             \
      _Pragma("unroll")                                                        \
      for (int nj = 0; nj < 2; ++nj) {                                         \
        acc[mi][2 + nj] = __builtin_amdgcn_mfma_f32_16x16x32_bf16(             \
            afr[mi][0], bfr[nj][0], acc[mi][2 + nj], 0, 0, 0);                 \
        acc[mi][2 + nj] = __builtin_amdgcn_mfma_f32_16x16x32_bf16(             \
            afr[mi][1], bfr[nj][1], acc[mi][2 + nj], 0, 0, 0);                 \
      }                                                                        \
    __builtin_amdgcn_s_setprio(0);                                             \
    if (u_ + 2 < NTt) asm volatile("s_waitcnt vmcnt(6)" ::: "memory");         \
    else              asm volatile("s_waitcnt vmcnt(0)" ::: "memory");         \
    BAR();                                                                     \
  } while (0)

  for (int u = 0; u < NTt; u += 2) {
    TILE(u, 0);
    TILE(u + 1, 1);
  }
#undef TILE

  // ---- LDS-coalesced epilogue: (x+bias)*0.1, full-line f32x4 stores ----
  // Pass p: waves with wr==p deposit their 128x256 half into LDS (f32,
  // col XOR'd by ((row>>2)&1)<<4 to break the 4-way q-group bank aliasing),
  // then all 8 waves stream 16 rows each as contiguous 1KB f32x4 stores.
  float* scratch = (float*)&lds[0][0][0][0];   // 32768 f32 = 128 x 256
  #pragma unroll
  for (int p = 0; p < 2; ++p) {
    if (wr == p) {
      #pragma unroll
      for (int ni = 0; ni < 4; ++ni) {
        const int col = (wc << 6) + ni * 16 + r;
        const float bv = bias[n0 + col];
        #pragma unroll
        for (int mi = 0; mi < 8; ++mi) {
          #pragma unroll
          for (int e = 0; e < 4; ++e) {
            const int row = mi * 16 + (q << 2) + e;
            const int cs  = col ^ (((row >> 2) & 1) << 4);
            scratch[row * 256 + cs] = (acc[mi][ni][e] + bv) * 0.1f;
          }
        }
      }
    }
    __syncthreads();
    #pragma unroll
    for (int rowi = 0; rowi < 16; ++rowi) {
      const int row = (wave << 4) + rowi;
      const int cb  = (lane << 2) ^ (((row >> 2) & 1) << 4);
      const f32x4 v4 = *(const f32x4*)&scratch[row * 256 + cb];
      *(f32x4*)&out[(size_t)(m0 + (p << 7) + row) * ldOut + n0 + (lane << 2)] = v4;
    }
    __syncthreads();
  }
}

// ---------------- LayerNorm over last dim (1024), f32 in -> bf16 out ----------------
__global__ void ln_kernel(const float* __restrict__ merged,
                          const float* __restrict__ lnw,
                          const float* __restrict__ lnb,
                          unsigned short* __restrict__ normed) {
  const int row = blockIdx.x;
  const float4 v = ((const float4*)(merged + (size_t)row * HIDDEN))[threadIdx.x];
  float s  = v.x + v.y + v.z + v.w;
  float ss = v.x * v.x + v.y * v.y + v.z * v.z + v.w * v.w;
  #pragma unroll
  for (int off = 32; off > 0; off >>= 1) {
    s  += __shfl_down(s, off, 64);
    ss += __shfl_down(ss, off, 64);
  }
  __shared__ float red[8];
  const int wvi = threadIdx.x >> 6;
  if ((threadIdx.x & 63) == 0) { red[wvi] = s; red[4 + wvi] = ss; }
  __syncthreads();
  s  = red[0] + red[1] + red[2] + red[3];
  ss = red[4] + red[5] + red[6] + red[7];
  const float mu  = s * (1.0f / HIDDEN);
  const float var = ss * (1.0f / HIDDEN) - mu * mu;
  const float rs  = rsqrtf(var + 1e-5f);
  const float4 w4 = ((const float4*)lnw)[threadIdx.x];
  const float4 b4 = ((const float4*)lnb)[threadIdx.x];
  ushort4 o;
  o.x = f2b((v.x - mu) * rs * w4.x + b4.x);
  o.y = f2b((v.y - mu) * rs * w4.y + b4.y);
  o.z = f2b((v.z - mu) * rs * w4.z + b4.z);
  o.w = f2b((v.w - mu) * rs * w4.w + b4.w);
  ((ushort4*)(normed + (size_t)row * HIDDEN))[threadIdx.x] = o;
}

extern "C" void kernel_launch(void* const* d_in, const int* in_sizes, int n_in,
                              void* d_out, int out_size, void* d_ws, size_t ws_size,
                              hipStream_t stream) {
  const int*   tokens = (const int*)d_in[0];
  const float* E      = (const float*)d_in[1];
  const float* Wc     = (const float*)d_in[2];
  const float* bc     = (const float*)d_in[3];
  const float* Wh     = (const float*)d_in[4];
  const float* bh     = (const float*)d_in[5];
  const float* Wm     = (const float*)d_in[6];
  const float* bm     = (const float*)d_in[7];
  const float* Wo     = (const float*)d_in[8];
  const float* bo     = (const float*)d_in[9];
  const float* lnw    = (const float*)d_in[10];
  const float* lnb    = (const float*)d_in[11];

  char* p = (char*)d_ws;
  unsigned short* WcT  = (unsigned short*)p; p += (size_t)HIDDEN * EMBED * 2;
  unsigned short* WhT  = (unsigned short*)p; p += (size_t)HIDDEN * EMBED * 2;
  unsigned short* WmT  = (unsigned short*)p; p += (size_t)HIDDEN * (2 * HIDDEN) * 2;
  unsigned short* WoT  = (unsigned short*)p; p += (size_t)VOCAB * HIDDEN * 2;
  unsigned short* emb  = (unsigned short*)p; p += (size_t)NROWS * EMBED * 2;
  unsigned short* hist = (unsigned short*)p; p += (size_t)NROWS * EMBED * 2;
  unsigned short* cat  = (unsigned short*)p; p += (size_t)NROWS * (2 * HIDDEN) * 2;
  float*          mrg  = (float*)p;          p += (size_t)NROWS * HIDDEN * 4;
  unsigned short* nrm  = (unsigned short*)p; p += (size_t)NROWS * HIDDEN * 2;
  float*          csum = (float*)p;          p += (size_t)BATCH * NCHUNK * EMBED * 4;
  if ((size_t)(p - (char*)d_ws) > ws_size)
    fprintf(stderr, "WS TOO SMALL: need %zu have %zu\n", (size_t)(p - (char*)d_ws), ws_size);

  // all 4 weight transposes in one launch (8768 x 64x64 tiles)
  transpose_all_kernel<<<8768, 256, 0, stream>>>(Wc, Wh, Wm, Wo, WcT, WhT, WmT, WoT);

  gather_sum_kernel<<<BATCH * NCHUNK, EMBED, 0, stream>>>(tokens, E, emb, csum);
  scan_excl_kernel<<<BATCH, EMBED, 0, stream>>>(csum);
  scan_emit_kernel<<<BATCH * NCHUNK, EMBED, 0, stream>>>(emb, csum, hist);

  const int nwgEnc = (NROWS / BM) * (HIDDEN / BN);   // 256 tiles per slice

  // cur_enc / hist_enc fused into one launch (z=2) -> concatenated [4096, 2048] bf16
  gemm_bt_kernel<0><<<dim3(nwgEnc, 1, 2), 256, 0, stream>>>(
      emb, WcT, bc, cat, NROWS, HIDDEN, EMBED, 2 * HIDDEN, 0,
      hist, WhT, bh, HIDDEN);
  // merged = relu(cat @ Wm + bm), kept f32 for LN accuracy
  gemm_bt_kernel<1><<<dim3(nwgEnc, 1, 1), 256, 0, stream>>>(
      cat, WmT, bm, mrg, NROWS, HIDDEN, 2 * HIDDEN, HIDDEN, 0,
      nullptr, nullptr, nullptr, 0);
  ln_kernel<<<NROWS, 256, 0, stream>>>(mrg, lnw, lnb, nrm);

  // logits = (normed @ Wo + bo) * 0.1 -> d_out f32, 256^2 deep-pipelined kernel
  const int nwgOut = (NROWS / 256) * (VOCAB / 256);  // 16 * 125 = 2000
  gemm256_out_kernel<<<dim3(nwgOut), 512, 0, stream>>>(
      nrm, WoT, bo, (float*)d_out, NROWS, VOCAB, HIDDEN, VOCAB);
}